// Round 6
// baseline (356.025 us; speedup 1.0000x reference)
//
#include <hip/hip_runtime.h>
#include <math.h>

#define NPG   200                 // nodes per graph
#define HDIM  128
#define NG    256
#define NT_T  (NG * NPG)          // 51200
#define EPG_  3200
#define E_T   (NG * EPG_)         // 819200
#define KP1   224                 // layer-1 K (200) padded to mult of 32
#define APITCH 224                // A' row pitch (zero cols >= 200)
#define XPAD  224                 // converted-X row pitch (zero cols >= 200)
#define TTP   232                 // Tt LDS pitch (shorts): 464B, 16B-aligned rows;
                                  // bank stride 116 words == 20 mod 32 -> <=2-way (free)
#define W1SZ  (256 * KP1)
#define W2SZ  (256 * HDIM)

typedef short short8 __attribute__((ext_vector_type(8)));
typedef float f32x4  __attribute__((ext_vector_type(4)));

__device__ __forceinline__ unsigned short f2bf(float f) {
    union { float f; unsigned int u; } v; v.f = f;
    unsigned int u = v.u;
    u += 0x7FFFu + ((u >> 16) & 1u);       // RNE
    return (unsigned short)(u >> 16);
}

// ---------------------------------------------------------------------------
// Both branches: per-graph adjacency via LDS u8 counters ->
// A' = count/max(deg,1) bf16, [branch][g][dst 0..199][src 0..223] (pad zero).
// ---------------------------------------------------------------------------
__global__ __launch_bounds__(256) void build_adj_kernel(const int* __restrict__ sc_ei,
                                                        const int* __restrict__ fc_ei,
                                                        unsigned short* __restrict__ A) {
    __shared__ unsigned int cnt[10000];    // 200*200 u8 counters packed in u32
    __shared__ float invdeg[200];
    const int branch = blockIdx.x >> 8;
    const int g = blockIdx.x & 255, t = threadIdx.x;
    const int* ei = branch ? fc_ei : sc_ei;

    for (int i = t; i < 10000; i += 256) cnt[i] = 0u;
    __syncthreads();

    const int ebase = g * EPG_;
    for (int i = t; i < EPG_; i += 256) {
        int src = ei[ebase + i];
        int dst = ei[E_T + ebase + i];
        int idx = (dst - g * NPG) * NPG + (src - g * NPG);
        atomicAdd(&cnt[idx >> 2], 1u << ((idx & 3) * 8));
    }
    __syncthreads();

    if (t < NPG) {
        unsigned int s = 0;
        for (int w = 0; w < 50; ++w) {
            unsigned int v = cnt[t * 50 + w];
            s += (v & 0xFFu) + ((v >> 8) & 0xFFu) + ((v >> 16) & 0xFFu) + ((v >> 24) & 0xFFu);
        }
        invdeg[t] = 1.0f / fmaxf((float)s, 1.0f);
    }
    __syncthreads();

    unsigned short* Ag = A + ((size_t)branch * NG + g) * NPG * APITCH;
    for (int q = t; q < NPG * (APITCH / 4); q += 256) {
        int row = q / 56;
        int c4  = (q - row * 56) * 4;
        float inv = invdeg[row];
        ushort4 o;
        unsigned short* po = (unsigned short*)&o;
#pragma unroll
        for (int j = 0; j < 4; ++j) {
            int col = c4 + j;
            float v = 0.0f;
            if (col < NPG) {
                unsigned int w = cnt[row * 50 + (col >> 2)];
                v = (float)((w >> ((col & 3) * 8)) & 0xFFu) * inv;
            }
            po[j] = f2bf(v);
        }
        *(ushort4*)&Ag[row * APITCH + c4] = o;
    }
}

// ---------------------------------------------------------------------------
// All 4 weight pairs -> packed W^T bf16: [br0 L1 | br1 L1 | br0 L2 | br1 L2].
// Rows 0..127 = wrel cols, 128..255 = wroot cols; k >= K zero-padded.
// ---------------------------------------------------------------------------
__global__ __launch_bounds__(256) void convert_w_kernel(
        const float* __restrict__ s1r, const float* __restrict__ s1o,
        const float* __restrict__ f1r, const float* __restrict__ f1o,
        const float* __restrict__ s2r, const float* __restrict__ s2o,
        const float* __restrict__ f2r, const float* __restrict__ f2o,
        unsigned short* __restrict__ wb) {
    int idx = blockIdx.x * 256 + threadIdx.x;
    if (idx >= 2 * W1SZ + 2 * W2SZ) return;
    float v = 0.0f;
    if (idx < 2 * W1SZ) {
        int branch = idx / W1SZ, rem = idx - branch * W1SZ;
        int c = rem / KP1, k = rem - c * KP1;
        const float* wr = branch ? f1r : s1r;
        const float* wo = branch ? f1o : s1o;
        if (k < 200) v = (c < 128) ? wr[(size_t)k * 128 + c] : wo[(size_t)k * 128 + (c - 128)];
    } else {
        int i2 = idx - 2 * W1SZ;
        int branch = i2 / W2SZ, rem = i2 - branch * W2SZ;
        int c = rem / HDIM, k = rem - c * HDIM;
        const float* wr = branch ? f2r : s2r;
        const float* wo = branch ? f2o : s2o;
        v = (c < 128) ? wr[(size_t)k * 128 + c] : wo[(size_t)k * 128 + (c - 128)];
    }
    wb[idx] = f2bf(v);
}

// ---------------------------------------------------------------------------
// Both branches: X fp32 [NT,200] -> bf16 [NT,224] (k>=200 zero).
// ---------------------------------------------------------------------------
__global__ __launch_bounds__(256) void convert_x_kernel(const float* __restrict__ sc_x,
                                                        const float* __restrict__ fc_x,
                                                        unsigned short* __restrict__ xb) {
    int c = blockIdx.x * 256 + threadIdx.x;     // chunk id: 28 chunks/node, 2 branches
    if (c >= 2 * NT_T * 28) return;
    int branch = c / (NT_T * 28);
    int rem = c - branch * (NT_T * 28);
    int node = rem / 28;
    int koff = (rem - node * 28) * 8;
    const float* x = branch ? fc_x : sc_x;
    uint4 o;
    if (koff < 200) {
        const float* p = x + (size_t)node * 200 + koff;
        float4 a = *(const float4*)p;
        float4 b = *(const float4*)(p + 4);
        o.x = (unsigned)f2bf(a.x) | ((unsigned)f2bf(a.y) << 16);
        o.y = (unsigned)f2bf(a.z) | ((unsigned)f2bf(a.w) << 16);
        o.z = (unsigned)f2bf(b.x) | ((unsigned)f2bf(b.y) << 16);
        o.w = (unsigned)f2bf(b.z) | ((unsigned)f2bf(b.w) << 16);
    } else {
        o.x = o.y = o.z = o.w = 0u;
    }
    *(uint4*)&xb[((size_t)branch * NT_T + node) * XPAD + koff] = o;
}

// ---------------------------------------------------------------------------
// Fused GraphConv layer. Block = (half, graph, branch), 256 threads / 4 waves.
// Phase 1 (2m x 2n waves): Tt[c][s] = sum_k X[g*200+s][k] * Wrel[half*64+c][k]
//   for c in [0,64) local -> LDS (29.7 KB -> 4 blocks/CU, 16 waves/CU).
// Phase 2 (2m x 2n waves): H[d][half*64+c] =
//   relu( sum_s Trel[c][s] A'[d][s] + sum_k Wroot[half*64+c][k] X[d][k] + brel )
//   (Troot folded into MFMA K-dim -> no Troot storage.)
// Pool fused: z[g, branch*256 + zlayer + half*64 + c] = scale * sum_d H.
// s/d >= 200: loads clamped; Tt garbage cols annihilated by A' zero columns;
// epilogue masked. VGPR budget: acc 56 + frags 36 + addr -> fits 128 cap.
// ---------------------------------------------------------------------------
template<bool IS_L1>
__global__ __launch_bounds__(256, 4) void layer_kernel(
        const unsigned short* __restrict__ Xb,     // L1 input, pitch 224
        const unsigned short* __restrict__ hin,    // L2 input, pitch 128
        const unsigned short* __restrict__ Wall,
        const unsigned short* __restrict__ Aall,
        const float* __restrict__ brel_sc, const float* __restrict__ brel_fc,
        unsigned short* __restrict__ Hout,
        float* __restrict__ z, int zlayer) {
    __shared__ alignas(16) short Tt[64 * TTP];   // 29,696 B
    __shared__ float zsum[64];

    const int tid = threadIdx.x;
    const int lane = tid & 63, wid = tid >> 6;     // 4 waves
    const int l15 = lane & 15, quad = lane >> 4;
    const int half = blockIdx.x;                   // 0/1: channel half
    const int g = blockIdx.y, branch = blockIdx.z;

    if (tid < 64) zsum[tid] = 0.0f;

    const int KITER = IS_L1 ? 7 : 4;
    const int XP    = IS_L1 ? XPAD : HDIM;         // input row pitch
    const int WP    = IS_L1 ? KP1 : HDIM;          // packed-W row pitch
    const unsigned short* X = (IS_L1 ? Xb : hin) + (size_t)branch * NT_T * XP;
    const unsigned short* W = Wall + (IS_L1 ? (size_t)branch * W1SZ
                                            : (size_t)2 * W1SZ + (size_t)branch * W2SZ);
    const unsigned short* Xg = X + (size_t)g * NPG * XP;

    // ======== Phase 1: M = s (14 tiles / 2 m-waves), N = c (4 tiles / 2 n-waves)
    {
        const int ms = wid & 1, ns = wid >> 1;
        int xoff[7];
#pragma unroll
        for (int mt = 0; mt < 7; ++mt) {
            int s = (ms * 7 + mt) * 16 + l15;
            if (s > NPG - 1) s = NPG - 1;          // clamp; garbage cols killed by A'=0
            xoff[mt] = s * XP + quad * 8;
        }
        int wrow[2];
#pragma unroll
        for (int nt = 0; nt < 2; ++nt)
            wrow[nt] = half * 64 + (ns * 2 + nt) * 16 + l15;   // rel rows 0..127

        f32x4 acc[7][2];
#pragma unroll
        for (int mt = 0; mt < 7; ++mt)
#pragma unroll
            for (int nt = 0; nt < 2; ++nt)
#pragma unroll
                for (int r = 0; r < 4; ++r) acc[mt][nt][r] = 0.0f;

#pragma unroll
        for (int ki = 0; ki < KITER; ++ki) {
            const int kb = ki * 32;
            short8 af[7];
#pragma unroll
            for (int mt = 0; mt < 7; ++mt)
                af[mt] = *(const short8*)&Xg[xoff[mt] + kb];
            short8 bf[2];
#pragma unroll
            for (int nt = 0; nt < 2; ++nt)
                bf[nt] = *(const short8*)&W[(size_t)wrow[nt] * WP + kb + quad * 8];
#pragma unroll
            for (int mt = 0; mt < 7; ++mt)
#pragma unroll
                for (int nt = 0; nt < 2; ++nt)
                    acc[mt][nt] = __builtin_amdgcn_mfma_f32_16x16x32_bf16(af[mt], bf[nt], acc[mt][nt], 0, 0, 0);
        }

        // D[m=s: quad*4+r][n=c: l15] -> Tt[c][s], 4 s-consecutive = ds_write_b64
#pragma unroll
        for (int mt = 0; mt < 7; ++mt) {
            int s0 = (ms * 7 + mt) * 16 + quad * 4;
#pragma unroll
            for (int nt = 0; nt < 2; ++nt) {
                int c = (ns * 2 + nt) * 16 + l15;          // local 0..63
                ushort4 o;
                unsigned short* po = (unsigned short*)&o;
#pragma unroll
                for (int r = 0; r < 4; ++r) po[r] = f2bf(acc[mt][nt][r]);
                *(ushort4*)&Tt[c * TTP + s0] = o;
            }
        }
    }
    __syncthreads();

    // ======== Phase 2: M = c (4 tiles / 2 m-waves), N = d (14 tiles / 2 n-waves)
    const int mw = wid & 1, nw = wid >> 1;
    const unsigned short* Ag = Aall + ((size_t)branch * NG + g) * NPG * APITCH;

    int dr[7];
#pragma unroll
    for (int nt = 0; nt < 7; ++nt) {
        int d = (nw * 7 + nt) * 16 + l15;
        dr[nt] = (d > NPG - 1) ? (NPG - 1) : d;
    }
    int crow[2];
#pragma unroll
    for (int mt = 0; mt < 2; ++mt) crow[mt] = (mw * 2 + mt) * 16 + l15;  // local c

    f32x4 acc2[2][7];
#pragma unroll
    for (int mt = 0; mt < 2; ++mt)
#pragma unroll
        for (int nt = 0; nt < 7; ++nt)
#pragma unroll
            for (int r = 0; r < 4; ++r) acc2[mt][nt][r] = 0.0f;

    // s-chunks: A = Trel (LDS), B = A' (global)
#pragma unroll
    for (int ki = 0; ki < 7; ++ki) {
        const int k0 = ki * 32 + quad * 8;
        short8 a2[2];
#pragma unroll
        for (int mt = 0; mt < 2; ++mt)
            a2[mt] = *(const short8*)&Tt[crow[mt] * TTP + k0];
        short8 b2[7];
#pragma unroll
        for (int nt = 0; nt < 7; ++nt)
            b2[nt] = *(const short8*)&Ag[(size_t)dr[nt] * APITCH + k0];
#pragma unroll
        for (int mt = 0; mt < 2; ++mt)
#pragma unroll
            for (int nt = 0; nt < 7; ++nt)
                acc2[mt][nt] = __builtin_amdgcn_mfma_f32_16x16x32_bf16(a2[mt], b2[nt], acc2[mt][nt], 0, 0, 0);
    }
    // root k-chunks: A = packed Wroot (rows 128 + half*64 + c), B = X rows d
#pragma unroll
    for (int ki = 0; ki < KITER; ++ki) {
        const int kb = ki * 32 + quad * 8;
        short8 a2[2];
#pragma unroll
        for (int mt = 0; mt < 2; ++mt)
            a2[mt] = *(const short8*)&W[(size_t)(128 + half * 64 + crow[mt]) * WP + kb];
        short8 b2[7];
#pragma unroll
        for (int nt = 0; nt < 7; ++nt)
            b2[nt] = *(const short8*)&Xg[(size_t)dr[nt] * XP + kb];
#pragma unroll
        for (int mt = 0; mt < 2; ++mt)
#pragma unroll
            for (int nt = 0; nt < 7; ++nt)
                acc2[mt][nt] = __builtin_amdgcn_mfma_f32_16x16x32_bf16(a2[mt], b2[nt], acc2[mt][nt], 0, 0, 0);
    }

    // Epilogue: D[m=c: quad*4+r][n=d: l15]; relu + brel, fused pool, H store (L1)
    const float* brel = branch ? brel_fc : brel_sc;
    unsigned short* Hb = Hout + (size_t)branch * NT_T * HDIM;

#pragma unroll
    for (int mt = 0; mt < 2; ++mt) {
        const int c0 = (mw * 2 + mt) * 16 + quad * 4;      // local ch 0..63
        float bb[4], part[4];
#pragma unroll
        for (int r = 0; r < 4; ++r) { bb[r] = brel[half * 64 + c0 + r]; part[r] = 0.0f; }
#pragma unroll
        for (int nt = 0; nt < 7; ++nt) {
            const int d = (nw * 7 + nt) * 16 + l15;
            if (d < NPG) {
                size_t node = (size_t)g * NPG + d;
                ushort4 o;
                unsigned short* po = (unsigned short*)&o;
#pragma unroll
                for (int r = 0; r < 4; ++r) {
                    float v = fmaxf(acc2[mt][nt][r] + bb[r], 0.0f);
                    part[r] += v;
                    po[r] = f2bf(v);
                }
                if (IS_L1) *(ushort4*)&Hb[node * HDIM + half * 64 + c0] = o;  // L2: pool only
            }
        }
        // butterfly over the 16 l15 lanes (d-dim), then 1 LDS atomic per channel
#pragma unroll
        for (int r = 0; r < 4; ++r) {
            float v = part[r];
            v += __shfl_xor(v, 1);
            v += __shfl_xor(v, 2);
            v += __shfl_xor(v, 4);
            v += __shfl_xor(v, 8);
            if (l15 == 0) atomicAdd(&zsum[c0 + r], v);
        }
    }
    __syncthreads();

    if (tid < 64)
        z[(size_t)g * 512 + branch * 256 + zlayer + half * 64 + tid] =
            zsum[tid] * (branch ? 1.0f : (1.0f / 200.0f));
}

// ---------------------------------------------------------------------------
// MLP head (fp32): z[512] -> relu(lin1)[128] -> relu(lin2)[64] -> lin3[2]
// -> log_softmax. One block per graph.
// ---------------------------------------------------------------------------
__global__ __launch_bounds__(128) void mlp_kernel(const float* __restrict__ z,
                                                  const float* __restrict__ w1, const float* __restrict__ b1,
                                                  const float* __restrict__ w2, const float* __restrict__ b2,
                                                  const float* __restrict__ w3, const float* __restrict__ b3,
                                                  float* __restrict__ out) {
    __shared__ float zs[512];
    __shared__ float l1[128];
    __shared__ float l2[64];
    __shared__ float logits[2];
    int g = blockIdx.x, t = threadIdx.x;

#pragma unroll
    for (int i = 0; i < 4; ++i) zs[t + 128 * i] = z[(size_t)g * 512 + t + 128 * i];
    __syncthreads();

    float s = b1[t];
#pragma unroll 8
    for (int k = 0; k < 512; ++k) s = fmaf(zs[k], w1[k * 128 + t], s);
    l1[t] = fmaxf(s, 0.0f);
    __syncthreads();

    if (t < 64) {
        float s2 = b2[t];
#pragma unroll 8
        for (int k = 0; k < 128; ++k) s2 = fmaf(l1[k], w2[k * 64 + t], s2);
        l2[t] = fmaxf(s2, 0.0f);
    }
    __syncthreads();

    if (t < 2) {
        float s3 = b3[t];
        for (int k = 0; k < 64; ++k) s3 = fmaf(l2[k], w3[k * 2 + t], s3);
        logits[t] = s3;
    }
    __syncthreads();

    if (t < 2) {
        float m = fmaxf(logits[0], logits[1]);
        float lse = m + logf(expf(logits[0] - m) + expf(logits[1] - m));
        out[(size_t)g * 2 + t] = logits[t] - lse;
    }
}

// ---------------------------------------------------------------------------
extern "C" void kernel_launch(void* const* d_in, const int* in_sizes, int n_in,
                              void* d_out, int out_size, void* d_ws, size_t ws_size,
                              hipStream_t stream) {
    const float* sc_x = (const float*)d_in[0];
    const float* fc_x = (const float*)d_in[1];
    const int* sc_ei  = (const int*)d_in[2];
    const int* fc_ei  = (const int*)d_in[3];
    const float* sc1_wrel = (const float*)d_in[5];
    const float* sc1_brel = (const float*)d_in[6];
    const float* sc1_wroot = (const float*)d_in[7];
    const float* sc2_wrel = (const float*)d_in[8];
    const float* sc2_brel = (const float*)d_in[9];
    const float* sc2_wroot = (const float*)d_in[10];
    const float* fc1_wrel = (const float*)d_in[11];
    const float* fc1_brel = (const float*)d_in[12];
    const float* fc1_wroot = (const float*)d_in[13];
    const float* fc2_wrel = (const float*)d_in[14];
    const float* fc2_brel = (const float*)d_in[15];
    const float* fc2_wroot = (const float*)d_in[16];
    const float* lin1_w = (const float*)d_in[17];
    const float* lin1_b = (const float*)d_in[18];
    const float* lin2_w = (const float*)d_in[19];
    const float* lin2_b = (const float*)d_in[20];
    const float* lin3_w = (const float*)d_in[21];
    const float* lin3_b = (const float*)d_in[22];

    // Workspace (shorts unless noted): Xb | A' | h | W | z  (~119 MB)
    unsigned short* Xb = (unsigned short*)d_ws;                 // 2*51200*224
    unsigned short* Ab = Xb + (size_t)2 * NT_T * XPAD;          // 2*256*200*224
    unsigned short* h  = Ab + (size_t)2 * NG * NPG * APITCH;    // 2*51200*128
    unsigned short* Wb = h + (size_t)2 * NT_T * HDIM;           // 2*(W1SZ+W2SZ)
    float* z = (float*)(Wb + (size_t)2 * (W1SZ + W2SZ));        // 256*512 fp32

    build_adj_kernel<<<2 * NG, 256, 0, stream>>>(sc_ei, fc_ei, Ab);
    convert_w_kernel<<<(2 * (W1SZ + W2SZ) + 255) / 256, 256, 0, stream>>>(
        sc1_wrel, sc1_wroot, fc1_wrel, fc1_wroot,
        sc2_wrel, sc2_wroot, fc2_wrel, fc2_wroot, Wb);
    convert_x_kernel<<<(2 * NT_T * 28 + 255) / 256, 256, 0, stream>>>(sc_x, fc_x, Xb);

    layer_kernel<true><<<dim3(2, NG, 2), 256, 0, stream>>>(
        Xb, h, Wb, Ab, sc1_brel, fc1_brel, h, z, 0);
    layer_kernel<false><<<dim3(2, NG, 2), 256, 0, stream>>>(
        Xb, h, Wb, Ab, sc2_brel, fc2_brel, h, z, 128);

    mlp_kernel<<<NG, 128, 0, stream>>>(z, lin1_w, lin1_b, lin2_w, lin2_b,
                                       lin3_w, lin3_b, (float*)d_out);
}

// Round 7
// 312.272 us; speedup vs baseline: 1.1401x; 1.1401x over previous
//
#include <hip/hip_runtime.h>
#include <math.h>

#define NPG   200                 // nodes per graph
#define HDIM  128
#define NG    256
#define NT_T  (NG * NPG)          // 51200
#define EPG_  3200
#define E_T   (NG * EPG_)         // 819200
#define KP1   224                 // layer-1 K (200) padded to mult of 32
#define APITCH 224                // A' row pitch (zero cols >= 200)
#define XPAD  224                 // converted-X row pitch (zero cols >= 200)
#define TTP   232                 // Tt LDS pitch (shorts): 464B, 16B-aligned rows
#define W1SZ  (256 * KP1)
#define W2SZ  (256 * HDIM)

typedef short short8 __attribute__((ext_vector_type(8)));
typedef float f32x4  __attribute__((ext_vector_type(4)));

__device__ __forceinline__ unsigned short f2bf(float f) {
    union { float f; unsigned int u; } v; v.f = f;
    unsigned int u = v.u;
    u += 0x7FFFu + ((u >> 16) & 1u);       // RNE
    return (unsigned short)(u >> 16);
}

// ---------------------------------------------------------------------------
// Both branches: per-graph adjacency via LDS u8 counters ->
// A' = count/max(deg,1) bf16, [branch][g][dst 0..199][src 0..223] (pad zero).
// ---------------------------------------------------------------------------
__global__ __launch_bounds__(256) void build_adj_kernel(const int* __restrict__ sc_ei,
                                                        const int* __restrict__ fc_ei,
                                                        unsigned short* __restrict__ A) {
    __shared__ unsigned int cnt[10000];    // 200*200 u8 counters packed in u32
    __shared__ float invdeg[200];
    const int branch = blockIdx.x >> 8;
    const int g = blockIdx.x & 255, t = threadIdx.x;
    const int* ei = branch ? fc_ei : sc_ei;

    for (int i = t; i < 10000; i += 256) cnt[i] = 0u;
    __syncthreads();

    const int ebase = g * EPG_;
    for (int i = t; i < EPG_; i += 256) {
        int src = ei[ebase + i];
        int dst = ei[E_T + ebase + i];
        int idx = (dst - g * NPG) * NPG + (src - g * NPG);
        atomicAdd(&cnt[idx >> 2], 1u << ((idx & 3) * 8));
    }
    __syncthreads();

    if (t < NPG) {
        unsigned int s = 0;
        for (int w = 0; w < 50; ++w) {
            unsigned int v = cnt[t * 50 + w];
            s += (v & 0xFFu) + ((v >> 8) & 0xFFu) + ((v >> 16) & 0xFFu) + ((v >> 24) & 0xFFu);
        }
        invdeg[t] = 1.0f / fmaxf((float)s, 1.0f);
    }
    __syncthreads();

    unsigned short* Ag = A + ((size_t)branch * NG + g) * NPG * APITCH;
    for (int q = t; q < NPG * (APITCH / 4); q += 256) {
        int row = q / 56;
        int c4  = (q - row * 56) * 4;
        float inv = invdeg[row];
        ushort4 o;
        unsigned short* po = (unsigned short*)&o;
#pragma unroll
        for (int j = 0; j < 4; ++j) {
            int col = c4 + j;
            float v = 0.0f;
            if (col < NPG) {
                unsigned int w = cnt[row * 50 + (col >> 2)];
                v = (float)((w >> ((col & 3) * 8)) & 0xFFu) * inv;
            }
            po[j] = f2bf(v);
        }
        *(ushort4*)&Ag[row * APITCH + c4] = o;
    }
}

// ---------------------------------------------------------------------------
// All 4 weight pairs -> packed W^T bf16: [br0 L1 | br1 L1 | br0 L2 | br1 L2].
// Rows 0..127 = wrel cols, 128..255 = wroot cols; k >= K zero-padded.
// ---------------------------------------------------------------------------
__global__ __launch_bounds__(256) void convert_w_kernel(
        const float* __restrict__ s1r, const float* __restrict__ s1o,
        const float* __restrict__ f1r, const float* __restrict__ f1o,
        const float* __restrict__ s2r, const float* __restrict__ s2o,
        const float* __restrict__ f2r, const float* __restrict__ f2o,
        unsigned short* __restrict__ wb) {
    int idx = blockIdx.x * 256 + threadIdx.x;
    if (idx >= 2 * W1SZ + 2 * W2SZ) return;
    float v = 0.0f;
    if (idx < 2 * W1SZ) {
        int branch = idx / W1SZ, rem = idx - branch * W1SZ;
        int c = rem / KP1, k = rem - c * KP1;
        const float* wr = branch ? f1r : s1r;
        const float* wo = branch ? f1o : s1o;
        if (k < 200) v = (c < 128) ? wr[(size_t)k * 128 + c] : wo[(size_t)k * 128 + (c - 128)];
    } else {
        int i2 = idx - 2 * W1SZ;
        int branch = i2 / W2SZ, rem = i2 - branch * W2SZ;
        int c = rem / HDIM, k = rem - c * HDIM;
        const float* wr = branch ? f2r : s2r;
        const float* wo = branch ? f2o : s2o;
        v = (c < 128) ? wr[(size_t)k * 128 + c] : wo[(size_t)k * 128 + (c - 128)];
    }
    wb[idx] = f2bf(v);
}

// ---------------------------------------------------------------------------
// Both branches: X fp32 [NT,200] -> bf16 [NT,224] (k>=200 zero).
// ---------------------------------------------------------------------------
__global__ __launch_bounds__(256) void convert_x_kernel(const float* __restrict__ sc_x,
                                                        const float* __restrict__ fc_x,
                                                        unsigned short* __restrict__ xb) {
    int c = blockIdx.x * 256 + threadIdx.x;     // chunk id: 28 chunks/node, 2 branches
    if (c >= 2 * NT_T * 28) return;
    int branch = c / (NT_T * 28);
    int rem = c - branch * (NT_T * 28);
    int node = rem / 28;
    int koff = (rem - node * 28) * 8;
    const float* x = branch ? fc_x : sc_x;
    uint4 o;
    if (koff < 200) {
        const float* p = x + (size_t)node * 200 + koff;
        float4 a = *(const float4*)p;
        float4 b = *(const float4*)(p + 4);
        o.x = (unsigned)f2bf(a.x) | ((unsigned)f2bf(a.y) << 16);
        o.y = (unsigned)f2bf(a.z) | ((unsigned)f2bf(a.w) << 16);
        o.z = (unsigned)f2bf(b.x) | ((unsigned)f2bf(b.y) << 16);
        o.w = (unsigned)f2bf(b.z) | ((unsigned)f2bf(b.w) << 16);
    } else {
        o.x = o.y = o.z = o.w = 0u;
    }
    *(uint4*)&xb[((size_t)branch * NT_T + node) * XPAD + koff] = o;
}

// ---------------------------------------------------------------------------
// Fused GraphConv layer, MERGED X-scan. Block = (half, graph, branch), 256 thr.
// Per-wave roles: ms = wid&1 -> node-tile set (7 x 16 rows),
//                 ns = wid>>1 -> channel-tile set (2 x 16 of this half's 64).
// X-scan K-loop (one pass over X!):
//   accT[s][c] += mfma(Xfrag, WrelFrag)     (transform, D[m=s][n=c])
//   accH[c][d] += mfma(WrootFrag, Xfrag)    (root term, D[m=c][n=d])
//   -> the same Xfrag serves as A-operand (rows s) and B-operand (cols d):
//      identical lane layout (row=l15, k=quad*8+j).
// accT -> Tt LDS (29.7 KB); barrier; agg K-loop over s:
//   accH[c][d] += mfma(TrelFrag(LDS), A'Frag)
// Epilogue: relu(accH + brel), fused pool, H store (L1 only).
// Registers: accT 56 + accH 56 + frags ~44 -> launch_bounds(256,2) gives the
// compiler ~65 free VGPRs to hoist next-iteration loads (ILP).
// ---------------------------------------------------------------------------
template<bool IS_L1>
__global__ __launch_bounds__(256, 2) void layer_kernel(
        const unsigned short* __restrict__ Xb,     // L1 input, pitch 224
        const unsigned short* __restrict__ hin,    // L2 input, pitch 128
        const unsigned short* __restrict__ Wall,
        const unsigned short* __restrict__ Aall,
        const float* __restrict__ brel_sc, const float* __restrict__ brel_fc,
        unsigned short* __restrict__ Hout,
        float* __restrict__ z, int zlayer) {
    __shared__ alignas(16) short Tt[64 * TTP];   // 29,696 B
    __shared__ float zsum[64];

    const int tid = threadIdx.x;
    const int lane = tid & 63, wid = tid >> 6;     // 4 waves
    const int l15 = lane & 15, quad = lane >> 4;
    const int half = blockIdx.x;                   // 0/1: channel half
    const int g = blockIdx.y, branch = blockIdx.z;

    if (tid < 64) zsum[tid] = 0.0f;

    const int KITER = IS_L1 ? 7 : 4;
    const int XP    = IS_L1 ? XPAD : HDIM;         // input row pitch
    const int WP    = IS_L1 ? KP1 : HDIM;          // packed-W row pitch
    const unsigned short* X = (IS_L1 ? Xb : hin) + (size_t)branch * NT_T * XP;
    const unsigned short* W = Wall + (IS_L1 ? (size_t)branch * W1SZ
                                            : (size_t)2 * W1SZ + (size_t)branch * W2SZ);
    const unsigned short* Xg = X + (size_t)g * NPG * XP;
    const unsigned short* Ag = Aall + ((size_t)branch * NG + g) * NPG * APITCH;

    const int ms = wid & 1;        // node-tile set
    const int ns = wid >> 1;       // channel-tile set

    // node rows (shared by X gather, A' gather, epilogue)
    int nrow[7];
#pragma unroll
    for (int mt = 0; mt < 7; ++mt) {
        int s = (ms * 7 + mt) * 16 + l15;
        nrow[mt] = (s > NPG - 1) ? (NPG - 1) : s;   // clamp; killed by A'=0 / mask
    }
    int wrel_row[2];
#pragma unroll
    for (int nt = 0; nt < 2; ++nt)
        wrel_row[nt] = half * 64 + (ns * 2 + nt) * 16 + l15;   // packed rows 0..127

    f32x4 accT[7][2];   // D[m=s][n=c]
    f32x4 accH[2][7];   // D[m=c][n=d]
#pragma unroll
    for (int mt = 0; mt < 7; ++mt)
#pragma unroll
        for (int nt = 0; nt < 2; ++nt)
#pragma unroll
            for (int r = 0; r < 4; ++r) { accT[mt][nt][r] = 0.0f; accH[nt][mt][r] = 0.0f; }

    // ======== Merged X-scan: transform + root term in one pass ========
#pragma unroll
    for (int ki = 0; ki < KITER; ++ki) {
        const int kb = ki * 32 + quad * 8;
        short8 xf[7];
#pragma unroll
        for (int mt = 0; mt < 7; ++mt)
            xf[mt] = *(const short8*)&Xg[nrow[mt] * XP + kb];
        short8 wr[2], wo[2];
#pragma unroll
        for (int nt = 0; nt < 2; ++nt) {
            wr[nt] = *(const short8*)&W[(size_t)wrel_row[nt] * WP + kb];
            wo[nt] = *(const short8*)&W[(size_t)(128 + wrel_row[nt]) * WP + kb];
        }
#pragma unroll
        for (int mt = 0; mt < 7; ++mt)
#pragma unroll
            for (int nt = 0; nt < 2; ++nt)
                accT[mt][nt] = __builtin_amdgcn_mfma_f32_16x16x32_bf16(xf[mt], wr[nt], accT[mt][nt], 0, 0, 0);
#pragma unroll
        for (int nt = 0; nt < 2; ++nt)
#pragma unroll
            for (int mt = 0; mt < 7; ++mt)
                accH[nt][mt] = __builtin_amdgcn_mfma_f32_16x16x32_bf16(wo[nt], xf[mt], accH[nt][mt], 0, 0, 0);
    }

    // accT -> Tt: lane holds (s = quad*4+r, c = l15) per tile
#pragma unroll
    for (int mt = 0; mt < 7; ++mt) {
        int s0 = (ms * 7 + mt) * 16 + quad * 4;
#pragma unroll
        for (int nt = 0; nt < 2; ++nt) {
            int c = (ns * 2 + nt) * 16 + l15;          // local 0..63
            ushort4 o;
            unsigned short* po = (unsigned short*)&o;
#pragma unroll
            for (int r = 0; r < 4; ++r) po[r] = f2bf(accT[mt][nt][r]);
            *(ushort4*)&Tt[c * TTP + s0] = o;
        }
    }
    __syncthreads();

    // ======== Agg K-loop over s: accH += Trel(LDS) x A'(global) ========
#pragma unroll
    for (int ki = 0; ki < 7; ++ki) {
        const int k0 = ki * 32 + quad * 8;
        short8 tf[2];
#pragma unroll
        for (int ct = 0; ct < 2; ++ct)
            tf[ct] = *(const short8*)&Tt[((ns * 2 + ct) * 16 + l15) * TTP + k0];
        short8 afr[7];
#pragma unroll
        for (int dt = 0; dt < 7; ++dt)
            afr[dt] = *(const short8*)&Ag[(size_t)nrow[dt] * APITCH + k0];
#pragma unroll
        for (int ct = 0; ct < 2; ++ct)
#pragma unroll
            for (int dt = 0; dt < 7; ++dt)
                accH[ct][dt] = __builtin_amdgcn_mfma_f32_16x16x32_bf16(tf[ct], afr[dt], accH[ct][dt], 0, 0, 0);
    }

    // Epilogue: lane holds (c = quad*4+r, d = l15); relu + brel, pool, H store
    const float* brel = branch ? brel_fc : brel_sc;
    unsigned short* Hb = Hout + (size_t)branch * NT_T * HDIM;

#pragma unroll
    for (int ct = 0; ct < 2; ++ct) {
        const int c0 = (ns * 2 + ct) * 16 + quad * 4;      // local ch 0..63
        float bb[4], part[4];
#pragma unroll
        for (int r = 0; r < 4; ++r) { bb[r] = brel[half * 64 + c0 + r]; part[r] = 0.0f; }
#pragma unroll
        for (int dt = 0; dt < 7; ++dt) {
            const int d = (ms * 7 + dt) * 16 + l15;
            if (d < NPG) {
                size_t node = (size_t)g * NPG + d;
                ushort4 o;
                unsigned short* po = (unsigned short*)&o;
#pragma unroll
                for (int r = 0; r < 4; ++r) {
                    float v = fmaxf(accH[ct][dt][r] + bb[r], 0.0f);
                    part[r] += v;
                    po[r] = f2bf(v);
                }
                if (IS_L1) *(ushort4*)&Hb[node * HDIM + half * 64 + c0] = o;  // L2: pool only
            }
        }
        // butterfly over the 16 l15 lanes (d-dim), then 1 LDS atomic per channel
#pragma unroll
        for (int r = 0; r < 4; ++r) {
            float v = part[r];
            v += __shfl_xor(v, 1);
            v += __shfl_xor(v, 2);
            v += __shfl_xor(v, 4);
            v += __shfl_xor(v, 8);
            if (l15 == 0) atomicAdd(&zsum[c0 + r], v);
        }
    }
    __syncthreads();

    if (tid < 64)
        z[(size_t)g * 512 + branch * 256 + zlayer + half * 64 + tid] =
            zsum[tid] * (branch ? 1.0f : (1.0f / 200.0f));
}

// ---------------------------------------------------------------------------
// MLP head (fp32): z[512] -> relu(lin1)[128] -> relu(lin2)[64] -> lin3[2]
// -> log_softmax. One block per graph.
// ---------------------------------------------------------------------------
__global__ __launch_bounds__(128) void mlp_kernel(const float* __restrict__ z,
                                                  const float* __restrict__ w1, const float* __restrict__ b1,
                                                  const float* __restrict__ w2, const float* __restrict__ b2,
                                                  const float* __restrict__ w3, const float* __restrict__ b3,
                                                  float* __restrict__ out) {
    __shared__ float zs[512];
    __shared__ float l1[128];
    __shared__ float l2[64];
    __shared__ float logits[2];
    int g = blockIdx.x, t = threadIdx.x;

#pragma unroll
    for (int i = 0; i < 4; ++i) zs[t + 128 * i] = z[(size_t)g * 512 + t + 128 * i];
    __syncthreads();

    float s = b1[t];
#pragma unroll 8
    for (int k = 0; k < 512; ++k) s = fmaf(zs[k], w1[k * 128 + t], s);
    l1[t] = fmaxf(s, 0.0f);
    __syncthreads();

    if (t < 64) {
        float s2 = b2[t];
#pragma unroll 8
        for (int k = 0; k < 128; ++k) s2 = fmaf(l1[k], w2[k * 64 + t], s2);
        l2[t] = fmaxf(s2, 0.0f);
    }
    __syncthreads();

    if (t < 2) {
        float s3 = b3[t];
        for (int k = 0; k < 64; ++k) s3 = fmaf(l2[k], w3[k * 2 + t], s3);
        logits[t] = s3;
    }
    __syncthreads();

    if (t < 2) {
        float m = fmaxf(logits[0], logits[1]);
        float lse = m + logf(expf(logits[0] - m) + expf(logits[1] - m));
        out[(size_t)g * 2 + t] = logits[t] - lse;
    }
}

// ---------------------------------------------------------------------------
extern "C" void kernel_launch(void* const* d_in, const int* in_sizes, int n_in,
                              void* d_out, int out_size, void* d_ws, size_t ws_size,
                              hipStream_t stream) {
    const float* sc_x = (const float*)d_in[0];
    const float* fc_x = (const float*)d_in[1];
    const int* sc_ei  = (const int*)d_in[2];
    const int* fc_ei  = (const int*)d_in[3];
    const float* sc1_wrel = (const float*)d_in[5];
    const float* sc1_brel = (const float*)d_in[6];
    const float* sc1_wroot = (const float*)d_in[7];
    const float* sc2_wrel = (const float*)d_in[8];
    const float* sc2_brel = (const float*)d_in[9];
    const float* sc2_wroot = (const float*)d_in[10];
    const float* fc1_wrel = (const float*)d_in[11];
    const float* fc1_brel = (const float*)d_in[12];
    const float* fc1_wroot = (const float*)d_in[13];
    const float* fc2_wrel = (const float*)d_in[14];
    const float* fc2_brel = (const float*)d_in[15];
    const float* fc2_wroot = (const float*)d_in[16];
    const float* lin1_w = (const float*)d_in[17];
    const float* lin1_b = (const float*)d_in[18];
    const float* lin2_w = (const float*)d_in[19];
    const float* lin2_b = (const float*)d_in[20];
    const float* lin3_w = (const float*)d_in[21];
    const float* lin3_b = (const float*)d_in[22];

    // Workspace (shorts unless noted): Xb | A' | h | W | z  (~119 MB)
    unsigned short* Xb = (unsigned short*)d_ws;                 // 2*51200*224
    unsigned short* Ab = Xb + (size_t)2 * NT_T * XPAD;          // 2*256*200*224
    unsigned short* h  = Ab + (size_t)2 * NG * NPG * APITCH;    // 2*51200*128
    unsigned short* Wb = h + (size_t)2 * NT_T * HDIM;           // 2*(W1SZ+W2SZ)
    float* z = (float*)(Wb + (size_t)2 * (W1SZ + W2SZ));        // 256*512 fp32

    build_adj_kernel<<<2 * NG, 256, 0, stream>>>(sc_ei, fc_ei, Ab);
    convert_w_kernel<<<(2 * (W1SZ + W2SZ) + 255) / 256, 256, 0, stream>>>(
        sc1_wrel, sc1_wroot, fc1_wrel, fc1_wroot,
        sc2_wrel, sc2_wroot, fc2_wrel, fc2_wroot, Wb);
    convert_x_kernel<<<(2 * NT_T * 28 + 255) / 256, 256, 0, stream>>>(sc_x, fc_x, Xb);

    layer_kernel<true><<<dim3(2, NG, 2), 256, 0, stream>>>(
        Xb, h, Wb, Ab, sc1_brel, fc1_brel, h, z, 0);
    layer_kernel<false><<<dim3(2, NG, 2), 256, 0, stream>>>(
        Xb, h, Wb, Ab, sc2_brel, fc2_brel, h, z, 128);

    mlp_kernel<<<NG, 128, 0, stream>>>(z, lin1_w, lin1_b, lin2_w, lin2_b,
                                       lin3_w, lin3_b, (float*)d_out);
}